// Round 8
// baseline (1627.333 us; speedup 1.0000x reference)
//
#include <hip/hip_runtime.h>
#include <hip/hip_bf16.h>

// ---------------------------------------------------------------------------
// myLSTM R8: exchange-free scan sized UNDER the allocator's revealed register
// budget (~128), with all Wh stream loads issued >=1 pass ahead.
//
// R2-R7 ledger: any partition NEEDING >128 regs of loop-invariant Wh got
// remat'd to just-in-time L2 loads (R5: 4240cy/step); asm-AGPR pinning (R7)
// hit an inline-asm hazard and failed correctness. R8 stops fighting:
//   per wave: 0 register tiles; 2 LDS tiles (16 slots = 128KB, XOR-swizzled);
//   6 streamed tiles via ping-pong buf[2][8] (64 VGPR) -- pass p computes
//   from buf[p&1], then refills that buffer with tile (p+2)%6, so loads are
//   in flight a full pass (~200+cy; passes 0,1 get the gates+barrier tail)
//   before use. Register need ~123 <= 128 grant -> no remat, by construction.
// Step model: L2 streams 384KB (~1600-2500cy, per-XCD L2 65% budget), LDS
// 16KB tiles + broadcasts (~500cy), MFMA 620cy, serial tail ~400cy ->
// ~2600-3300cy/step.
//
//   prep_all  : x->bf16 ; Wi -> WiT [1024][256] bf16 ; Wh -> WhP permuted
//               [1024][256] bf16, row' = w*128 + rt*16 + q*4 + r  <->
//               col_nat = gate(r)*256 + unit(w*32 + rt*4 + q).
//   xg_gemm   : xg = x@Wi + b (bf16 MFMA 128x128), PERMUTED [b][t][u][gate].
//   lstm_scan : 64 WGs (one batch each), 512 thr = 8 waves, 2/SIMD (132KB
//               LDS -> 1 WG/CU). Wave w owns Wh rows' [w*128,+128) = 8 tiles:
//               rt 0..5 streamed, rt 6..7 LDS. h_{t-1} (512B) double-buffered
//               in LDS, broadcast B-fragment (hb8). Extraction: lane l16==rt
//               owns unit w*32 + l16*4 + quad. One barrier/step.
//   attn_head : fused attention + MLP head (block-local per batch).
// ---------------------------------------------------------------------------

typedef __attribute__((ext_vector_type(8))) short short8;   // 8 x bf16 (4 VGPR)
typedef __attribute__((ext_vector_type(4))) float float4v;  // MFMA acc

__device__ __forceinline__ unsigned short f2bf(float f) {  // RNE f32->bf16
  unsigned u = __builtin_bit_cast(unsigned, f);
  return (unsigned short)((u + 0x7fffu + ((u >> 16) & 1u)) >> 16);
}
__device__ __forceinline__ float bf2f(unsigned short h) {
  return __builtin_bit_cast(float, ((unsigned)h) << 16);
}
__device__ __forceinline__ float bcl(unsigned u) {  // low bf16 of dword
  return __builtin_bit_cast(float, u << 16);
}
__device__ __forceinline__ float bch(unsigned u) {  // high bf16 of dword
  return __builtin_bit_cast(float, u & 0xffff0000u);
}
// v_rcp_f32 (1 ulp) instead of precise div: error ~1e-7, invisible vs bf16.
__device__ __forceinline__ float sigm(float x) {
  return __builtin_amdgcn_rcpf(1.f + __expf(-x));
}
__device__ __forceinline__ float tanh_f(float x) {
  return 1.f - 2.f * __builtin_amdgcn_rcpf(1.f + __expf(2.f * x));
}

// ---------------------------------------------------------------- prep (fused)
// blocks [0,8192)    : x fp32 -> bf16                (8,388,608 elems)
// blocks [8192,8448) : Wi [256,1024] -> WiT [1024][256] bf16
// blocks [8448,8704) : Wh [256,1024] -> WhP [1024][256] bf16, row-permuted
__global__ void prep_all(const float* __restrict__ x,
                         const float* __restrict__ Wi,
                         const float* __restrict__ Wh,
                         unsigned short* __restrict__ xbf,
                         unsigned short* __restrict__ WiT,
                         unsigned short* __restrict__ WhP) {
  const int bid = blockIdx.x, tid = threadIdx.x;
  if (bid < 8192) {
    size_t i = ((size_t)bid * 256 + tid) * 4;
    float4 v = *(const float4*)&x[i];
    unsigned long long pk = (unsigned long long)f2bf(v.x)
                          | ((unsigned long long)f2bf(v.y) << 16)
                          | ((unsigned long long)f2bf(v.z) << 32)
                          | ((unsigned long long)f2bf(v.w) << 48);
    *(unsigned long long*)&xbf[i] = pk;
  } else if (bid < 8448) {
    size_t i = ((size_t)(bid - 8192) * 256 + tid) * 4;
    float4 v = *(const float4*)&Wi[i];
    int k = (int)(i >> 10), n = (int)(i & 1023);
    WiT[(size_t)(n + 0) * 256 + k] = f2bf(v.x);
    WiT[(size_t)(n + 1) * 256 + k] = f2bf(v.y);
    WiT[(size_t)(n + 2) * 256 + k] = f2bf(v.z);
    WiT[(size_t)(n + 3) * 256 + k] = f2bf(v.w);
  } else {
    size_t i0 = ((size_t)(bid - 8448) * 256 + tid) * 4;
    int row = (int)(i0 >> 8);  // row' (same for all 4 elems)
    // row' = w*128 + rt*16 + q*4 + r -> col_nat = r*256 + w*32 + rt*4 + q
    int colnat = (row & 3) * 256 + (row >> 7) * 32 + ((row >> 4) & 7) * 4 +
                 ((row >> 2) & 3);
    unsigned long long pk = 0;
#pragma unroll
    for (int j = 0; j < 4; ++j) {
      int k = (int)((i0 + j) & 255);
      pk |= (unsigned long long)f2bf(Wh[(size_t)k * 1024 + colnat]) << (16 * j);
    }
    *(unsigned long long*)&WhP[i0] = pk;
  }
}

// ---------------------------------------------------------------- xg = x@Wi+b
#define XKP 40  // LDS k-pitch (shorts): 80B rows -> 16B-aligned b128, ~2-way banks
__global__ __launch_bounds__(256) void xg_gemm(const unsigned short* __restrict__ xbf,
                                               const unsigned short* __restrict__ WiT,
                                               const float* __restrict__ bias,
                                               unsigned short* __restrict__ xg) {
  __shared__ unsigned short As[128 * XKP];
  __shared__ unsigned short Bs[128 * XKP];
  const int tid = threadIdx.x;
  const int n0 = blockIdx.x * 128, m0 = blockIdx.y * 128;
  const int wave = tid >> 6, lane = tid & 63, quad = lane >> 4, l16 = lane & 15;
  const int wm = wave >> 1, wn = wave & 1;

  float4v acc[4][4];
#pragma unroll
  for (int i = 0; i < 4; ++i)
#pragma unroll
    for (int j = 0; j < 4; ++j) acc[i][j] = (float4v){0.f, 0.f, 0.f, 0.f};

  const int rr = tid >> 2, c8 = (tid & 3) * 8;  // staging coords (16B per thread)
  for (int k0 = 0; k0 < 256; k0 += 32) {
#pragma unroll
    for (int pp = 0; pp < 2; ++pp) {
      int r = pp * 64 + rr;
      *(uint4*)&As[r * XKP + c8] = *(const uint4*)&xbf[(size_t)(m0 + r) * 256 + k0 + c8];
      *(uint4*)&Bs[r * XKP + c8] = *(const uint4*)&WiT[(size_t)(n0 + r) * 256 + k0 + c8];
    }
    __syncthreads();
#pragma unroll
    for (int mt = 0; mt < 4; ++mt) {
      short8 af = *(const short8*)&As[(wm * 64 + mt * 16 + l16) * XKP + quad * 8];
#pragma unroll
      for (int nt = 0; nt < 4; ++nt) {
        short8 bf = *(const short8*)&Bs[(wn * 64 + nt * 16 + l16) * XKP + quad * 8];
        acc[mt][nt] = __builtin_amdgcn_mfma_f32_16x16x32_bf16(af, bf, acc[mt][nt], 0, 0, 0);
      }
    }
    __syncthreads();
  }
  // epilogue: +bias, bf16 store, PERMUTED layout for the scan:
  //   xg[((b*512 + t)*256 + u)*4 + gate]   (4 gates of a unit contiguous, 8B)
#pragma unroll
  for (int nt = 0; nt < 4; ++nt) {
    int col = n0 + wn * 64 + nt * 16 + l16;
    int gate = col >> 8, u = col & 255;
    float bv = bias[col];
#pragma unroll
    for (int mt = 0; mt < 4; ++mt) {
#pragma unroll
      for (int r = 0; r < 4; ++r) {
        int row = m0 + wm * 64 + mt * 16 + quad * 4 + r;
        int b = row >> 9, t = row & 511;
        xg[(((size_t)b * 512 + t) * 256 + u) * 4 + gate] = f2bf(acc[mt][nt][r] + bv);
      }
    }
  }
}

// ---------------------------------------------------------------- LSTM scan
// 64 WGs, one batch each. 512 threads = 8 waves, 2 waves/SIMD (132KB LDS ->
// 1 WG/CU). Wave w owns Wh rows' [w*128, w*128+128) = 8 tiles:
// rt 0..5 streamed from L2 (ping-pong 2x32-reg buffers, issued 1+ pass
// ahead), rt 6..7 LDS slots wave*2+{0,1} (XOR-swizzled).
// Lane (quad, l16<8) owns unit u = w*32 + l16*4 + quad; act tile rt == l16.
__global__ __launch_bounds__(512) void lstm_scan(
    const unsigned short* __restrict__ WhP,  // [1024][256] bf16 (permuted rows)
    const unsigned short* __restrict__ xg,   // [b][t][u][gate] bf16
    unsigned short* __restrict__ hout) {
  __shared__ unsigned short WhL[16 * 4096];     // 16 slots x 8KB = 131072 B
  __shared__ unsigned short hA[2][256];         // 1 KB, double-buffered h
  const int tid = threadIdx.x;
  const int b = blockIdx.x;  // batch
  const int wave = tid >> 6, lane = tid & 63, quad = lane >> 4, l16 = lane & 15;

  // ---- 2 LDS tiles (rt = 6,7) -> slots wave*2, wave*2+1, XOR-swizzled
#pragma unroll
  for (int i = 0; i < 16; ++i) {
    int rt = 6 + (i >> 3);
    int chunk = (i & 7) * 64 + lane;     // 512 16B-chunks per tile
    int rw = chunk >> 5, ch = chunk & 31;
    uint4 v = *(const uint4*)&WhP[((size_t)wave * 128 + rt * 16 + rw) * 256 + ch * 8];
    *(uint4*)((char*)WhL + (wave * 2 + rt - 6) * 8192 + rw * 512 +
              ((ch * 16) ^ ((rw & 7) << 4))) = v;
  }
  ((unsigned short*)hA)[tid] = 0;        // h_{-1} = 0 (both buffers; 512 shorts)

  const bool act = (l16 < 8);
  const int u = wave * 32 + l16 * 4 + quad;    // this lane's unit (if act)
  const unsigned short* xgp = xg + ((size_t)b * 512 * 256 + u) * 4;
  unsigned short* houtp = hout + (size_t)b * 512 * 256 + u;
  const char* ldsT = (const char*)WhL + wave * 2 * 8192 + l16 * 512;
  // stream base: tile rt lives at sp + rt*4096 (shorts)
  const unsigned short* sp = WhP + ((size_t)wave * 128 + l16) * 256 + quad * 8;
  float c = 0.f;

  // prologue: tiles 0,1 into the ping-pong buffers (in flight across barrier)
  short8 buf[2][8];
#pragma unroll
  for (int kt = 0; kt < 8; ++kt) buf[0][kt] = *(const short8*)&sp[0 * 4096 + kt * 32];
#pragma unroll
  for (int kt = 0; kt < 8; ++kt) buf[1][kt] = *(const short8*)&sp[1 * 4096 + kt * 32];
  __syncthreads();

  for (int t = 0; t < 512; ++t) {
    // xg(t): 4 gates of this lane's unit, 8B (consumed at step end)
    unsigned long long xv = 0;
    if (act) xv = *(const unsigned long long*)(xgp + (size_t)t * 1024);

    // h_{t-1} broadcast fragments (conflict-free broadcast reads)
    const char* hbuf = (const char*)hA[t & 1];
    short8 hb8[8];
#pragma unroll
    for (int kt = 0; kt < 8; ++kt)
      hb8[kt] = *(const short8*)(hbuf + kt * 64 + quad * 16);

    float4v g4 = (float4v){0.f, 0.f, 0.f, 0.f};

    // ---- stream passes 0..5: compute from buf[p&1], then refill that
    // buffer with tile (p+2)%6 (>=1 full pass of distance before use;
    // passes 4,5 refill tiles 0,1 for the NEXT step -> huge distance).
#pragma unroll
    for (int p = 0; p < 6; ++p) {
      float4v a = (float4v){0.f, 0.f, 0.f, 0.f};
#pragma unroll
      for (int kt = 0; kt < 8; ++kt)
        a = __builtin_amdgcn_mfma_f32_16x16x32_bf16(buf[p & 1][kt], hb8[kt], a, 0, 0, 0);
      if (l16 == p) g4 = a;
      const int nrt = (p + 2) % 6;       // compile-time after unroll
#pragma unroll
      for (int kt = 0; kt < 8; ++kt)
        buf[p & 1][kt] = *(const short8*)&sp[nrt * 4096 + kt * 32];
    }

    // ---- LDS passes: tiles rt = 6,7 (swizzled)
#pragma unroll
    for (int p = 0; p < 2; ++p) {
      float4v a = (float4v){0.f, 0.f, 0.f, 0.f};
#pragma unroll
      for (int kt = 0; kt < 8; ++kt) {
        short8 al = *(const short8*)(ldsT + p * 8192 +
                                     ((kt * 64 + quad * 16) ^ ((l16 & 7) << 4)));
        a = __builtin_amdgcn_mfma_f32_16x16x32_bf16(al, hb8[kt], a, 0, 0, 0);
      }
      if (l16 == 6 + p) g4 = a;
    }

    // ---- gates (active lanes own one unit each)
    if (act) {
      float gi = g4[0] + bf2f((unsigned short)(xv));
      float gf = g4[1] + bf2f((unsigned short)(xv >> 16));
      float gG = g4[2] + bf2f((unsigned short)(xv >> 32));
      float go = g4[3] + bf2f((unsigned short)(xv >> 48));
      float cc = sigm(gf) * c + sigm(gi) * tanh_f(gG);
      c = cc;
      unsigned short h16 = f2bf(sigm(go) * tanh_f(cc));
      hA[(t + 1) & 1][u] = h16;          // next buffer (disjoint from readers)
      houtp[(size_t)t * 256] = h16;      // h history for attention
    }
    __syncthreads();                     // ONE barrier per step
  }
}

// --------------------------------------------------- attention + head (fused)
__global__ __launch_bounds__(256) void attn_head(
    const unsigned short* __restrict__ hout,
    const float* __restrict__ Wq, const float* __restrict__ bq,
    const float* __restrict__ Wk, const float* __restrict__ bk,
    const float* __restrict__ Wv, const float* __restrict__ bv,
    const float* __restrict__ Wo, const float* __restrict__ bo,
    const float* __restrict__ W1, const float* __restrict__ b1,
    const float* __restrict__ W2, const float* __restrict__ b2,
    float* __restrict__ out) {
  __shared__ float h0S[256], q0S[256], red[256], usS[256], sS[512], hb4[4][256];
  __shared__ float oS[256], o1S[256], zS[32], cbS;
  const int b = blockIdx.x, tid = threadIdx.x, wave = tid >> 6, lane = tid & 63;
  const size_t hb_base = (size_t)b * 512 * 256;

  // ---- q0 = h0@Wq+bq ; u = Wk@(scale*q0) ; cb = scale*q0.bk
  h0S[tid] = bf2f(hout[hb_base + tid]);
  __syncthreads();
  float a = 0.f;
  for (int k = 0; k < 256; ++k) a += h0S[k] * Wq[(size_t)k * 256 + tid];
  q0S[tid] = a + bq[tid];
  __syncthreads();
  red[tid] = q0S[tid] * bk[tid];
  __syncthreads();
  for (int s = 128; s > 0; s >>= 1) {
    if (tid < s) red[tid] += red[tid + s];
    __syncthreads();
  }
  if (tid == 0) cbS = 0.0625f * red[0];
  float acq = 0.f;
  const float* wr = &Wk[(size_t)tid * 256];
  for (int e = 0; e < 256; e += 4) {
    float4 w = *(const float4*)&wr[e];
    acq += w.x * q0S[e] + w.y * q0S[e + 1] + w.z * q0S[e + 2] + w.w * q0S[e + 3];
  }
  usS[tid] = 0.0625f * acq;
  __syncthreads();

  // ---- scores = u.h[b,t]+cb -> softmax -> hbar = sum attn*h
  const float u0 = usS[lane * 4 + 0], u1 = usS[lane * 4 + 1];
  const float u2 = usS[lane * 4 + 2], u3 = usS[lane * 4 + 3];
  const float cbv = cbS;
  for (int i = 0; i < 128; ++i) {
    int t = i * 4 + wave;
    unsigned long long hv = *(const unsigned long long*)&hout[hb_base + (size_t)t * 256 + lane * 4];
    unsigned lo = (unsigned)hv, hi = (unsigned)(hv >> 32);
    float p = u0 * bcl(lo) + u1 * bch(lo) + u2 * bcl(hi) + u3 * bch(hi);
    for (int m = 1; m < 64; m <<= 1) p += __shfl_xor(p, m, 64);
    if (lane == 0) sS[t] = p + cbv;
  }
  __syncthreads();
  red[tid] = fmaxf(sS[tid], sS[tid + 256]);
  __syncthreads();
  for (int s = 128; s > 0; s >>= 1) {
    if (tid < s) red[tid] = fmaxf(red[tid], red[tid + s]);
    __syncthreads();
  }
  float mx = red[0];
  __syncthreads();
  float e0 = __expf(sS[tid] - mx), e1 = __expf(sS[tid + 256] - mx);
  sS[tid] = e0; sS[tid + 256] = e1;
  red[tid] = e0 + e1;
  __syncthreads();
  for (int s = 128; s > 0; s >>= 1) {
    if (tid < s) red[tid] += red[tid + s];
    __syncthreads();
  }
  float inv = 1.f / red[0];
  float a0 = 0.f, a1 = 0.f, a2 = 0.f, a3 = 0.f;
  const int d0 = lane * 4;
  for (int i = 0; i < 128; ++i) {
    int t = wave * 128 + i;
    float w = sS[t];
    unsigned long long hv = *(const unsigned long long*)&hout[hb_base + (size_t)t * 256 + d0];
    unsigned lo = (unsigned)hv, hi = (unsigned)(hv >> 32);
    a0 += w * bcl(lo); a1 += w * bch(lo); a2 += w * bcl(hi); a3 += w * bch(hi);
  }
  hb4[wave][d0] = a0; hb4[wave][d0 + 1] = a1; hb4[wave][d0 + 2] = a2; hb4[wave][d0 + 3] = a3;
  __syncthreads();
  h0S[tid] = (hb4[0][tid] + hb4[1][tid] + hb4[2][tid] + hb4[3][tid]) * inv;  // hbar
  __syncthreads();

  // ---- head: o0=hbar@Wv+bv ; o1=o0@Wo+bo ; z=relu(o1@W1+b1) ; out=z@W2+b2
  a = 0.f;
  for (int k = 0; k < 256; ++k) a += h0S[k] * Wv[(size_t)k * 256 + tid];
  oS[tid] = a + bv[tid];
  __syncthreads();
  a = 0.f;
  for (int k = 0; k < 256; ++k) a += oS[k] * Wo[(size_t)k * 256 + tid];
  o1S[tid] = a + bo[tid];
  __syncthreads();
  if (tid < 32) {
    a = 0.f;
    for (int k = 0; k < 256; ++k) a += o1S[k] * W1[k * 32 + tid];
    zS[tid] = fmaxf(a + b1[tid], 0.f);
  }
  __syncthreads();
  if (tid < 3) {
    a = 0.f;
    for (int j = 0; j < 32; ++j) a += zS[j] * W2[j * 3 + tid];
    out[b * 3 + tid] = a + b2[tid];
  }
}

// ---------------------------------------------------------------- launch
extern "C" void kernel_launch(void* const* d_in, const int* in_sizes, int n_in,
                              void* d_out, int out_size, void* d_ws, size_t ws_size,
                              hipStream_t stream) {
  const float* x  = (const float*)d_in[0];
  const float* Wi = (const float*)d_in[1];
  const float* Wh = (const float*)d_in[2];
  const float* bG = (const float*)d_in[3];
  const float* Wq = (const float*)d_in[4];
  const float* bq = (const float*)d_in[5];
  const float* Wk = (const float*)d_in[6];
  const float* bk = (const float*)d_in[7];
  const float* Wv = (const float*)d_in[8];
  const float* bv = (const float*)d_in[9];
  const float* Wo = (const float*)d_in[10];
  const float* bo = (const float*)d_in[11];
  const float* W1 = (const float*)d_in[12];
  const float* b1 = (const float*)d_in[13];
  const float* W2 = (const float*)d_in[14];
  const float* b2 = (const float*)d_in[15];
  float* out = (float*)d_out;
  char* ws = (char*)d_ws;

  unsigned short* xg   = (unsigned short*)(ws);              // 67,108,864 B
  unsigned short* hout = (unsigned short*)(ws + 67108864);   // 16,777,216 B
  unsigned short* xbf  = (unsigned short*)(ws + 83886080);   // 16,777,216 B
  unsigned short* WiT  = (unsigned short*)(ws + 100663296);  //    524,288 B
  unsigned short* WhP  = (unsigned short*)(ws + 101187584);  //    524,288 B
  // total ~101.7 MB of workspace

  prep_all<<<dim3(8704), dim3(256), 0, stream>>>(x, Wi, Wh, xbf, WiT, WhP);
  xg_gemm<<<dim3(8, 256), dim3(256), 0, stream>>>(xbf, WiT, bG, xg);
  lstm_scan<<<dim3(64), dim3(512), 0, stream>>>(WhP, xg, hout);
  attn_head<<<dim3(64), dim3(256), 0, stream>>>(hout, Wq, bq, Wk, bk, Wv, bv,
                                                Wo, bo, W1, b1, W2, b2, out);
}

// Round 9
// 1329.133 us; speedup vs baseline: 1.2244x; 1.2244x over previous
//
#include <hip/hip_runtime.h>
#include <hip/hip_bf16.h>

// ---------------------------------------------------------------------------
// myLSTM R9: R5 structure (best verified: scan 906us) with the 8 MFMA passes
// restructured into 4 INTERLEAVED PAIRS to hide MFMA dependent-chain latency.
//
// R5/R8 ledger: R5 (3 AGPR-resident tiles + 2 LDS + 3 streamed per wave,
// VGPR=128 w/ frA in AGPRs) = 4240cy/step. R8 (0 resident, 6 streamed,
// ping-pong WAR) = 6400cy/step -> residency + dedicated stream buffers win.
// R5's remaining serialization: each pass = 8 MFMAs chained on ONE acc;
// 8 passes back-to-back => ~1300cy exposed dependent latency that the
// barrier-locked 2 waves/SIMD can't hide. R9 interleaves pass pairs
// (a0/a1 alternate per kt -> same-acc MFMAs 2 issues apart), keeping R5's
// partition, buffers, and stream issue points EXACTLY.
//
//   prep_all  : x->bf16 ; Wi -> WiT [1024][256] bf16 ; Wh -> WhP permuted
//               [1024][256] bf16, row' = w*128 + rt*16 + q*4 + r  <->
//               col_nat = gate(r)*256 + unit(w*32 + rt*4 + q).
//   xg_gemm   : xg = x@Wi + b (bf16 MFMA 128x128), PERMUTED [b][t][u][gate].
//   lstm_scan : 64 WGs (one batch each), 512 thr = 8 waves, 2/SIMD.
//               Wave w owns Wh rows' [w*128,+128) = 8 tiles:
//               rt 0..2 resident (AGPR via allocator), rt 3..4 LDS
//               (XOR-swizzled), rt 5..7 streamed (sb: tile5 at step top,
//               sc: tile6 after pair01, sb reload tile7 after pair45).
//               Pairs: (0,1) reg-reg, (2,3) reg-LDS0, (4,5) LDS1-sb,
//               (6,7) sc-sb. Extraction: lane l16==p owns unit
//               w*32 + l16*4 + quad. One barrier/step.
//   attn_head : fused attention + MLP head (block-local per batch).
// ---------------------------------------------------------------------------

typedef __attribute__((ext_vector_type(8))) short short8;   // 8 x bf16 (4 VGPR)
typedef __attribute__((ext_vector_type(4))) float float4v;  // MFMA acc

__device__ __forceinline__ unsigned short f2bf(float f) {  // RNE f32->bf16
  unsigned u = __builtin_bit_cast(unsigned, f);
  return (unsigned short)((u + 0x7fffu + ((u >> 16) & 1u)) >> 16);
}
__device__ __forceinline__ float bf2f(unsigned short h) {
  return __builtin_bit_cast(float, ((unsigned)h) << 16);
}
__device__ __forceinline__ float bcl(unsigned u) {  // low bf16 of dword
  return __builtin_bit_cast(float, u << 16);
}
__device__ __forceinline__ float bch(unsigned u) {  // high bf16 of dword
  return __builtin_bit_cast(float, u & 0xffff0000u);
}
// v_rcp_f32 (1 ulp) instead of precise div: error ~1e-7, invisible vs bf16.
__device__ __forceinline__ float sigm(float x) {
  return __builtin_amdgcn_rcpf(1.f + __expf(-x));
}
__device__ __forceinline__ float tanh_f(float x) {
  return 1.f - 2.f * __builtin_amdgcn_rcpf(1.f + __expf(2.f * x));
}

// ---------------------------------------------------------------- prep (fused)
// blocks [0,8192)    : x fp32 -> bf16                (8,388,608 elems)
// blocks [8192,8448) : Wi [256,1024] -> WiT [1024][256] bf16
// blocks [8448,8704) : Wh [256,1024] -> WhP [1024][256] bf16, row-permuted
__global__ void prep_all(const float* __restrict__ x,
                         const float* __restrict__ Wi,
                         const float* __restrict__ Wh,
                         unsigned short* __restrict__ xbf,
                         unsigned short* __restrict__ WiT,
                         unsigned short* __restrict__ WhP) {
  const int bid = blockIdx.x, tid = threadIdx.x;
  if (bid < 8192) {
    size_t i = ((size_t)bid * 256 + tid) * 4;
    float4 v = *(const float4*)&x[i];
    unsigned long long pk = (unsigned long long)f2bf(v.x)
                          | ((unsigned long long)f2bf(v.y) << 16)
                          | ((unsigned long long)f2bf(v.z) << 32)
                          | ((unsigned long long)f2bf(v.w) << 48);
    *(unsigned long long*)&xbf[i] = pk;
  } else if (bid < 8448) {
    size_t i = ((size_t)(bid - 8192) * 256 + tid) * 4;
    float4 v = *(const float4*)&Wi[i];
    int k = (int)(i >> 10), n = (int)(i & 1023);
    WiT[(size_t)(n + 0) * 256 + k] = f2bf(v.x);
    WiT[(size_t)(n + 1) * 256 + k] = f2bf(v.y);
    WiT[(size_t)(n + 2) * 256 + k] = f2bf(v.z);
    WiT[(size_t)(n + 3) * 256 + k] = f2bf(v.w);
  } else {
    size_t i0 = ((size_t)(bid - 8448) * 256 + tid) * 4;
    int row = (int)(i0 >> 8);  // row' (same for all 4 elems)
    // row' = w*128 + rt*16 + q*4 + r -> col_nat = r*256 + w*32 + rt*4 + q
    int colnat = (row & 3) * 256 + (row >> 7) * 32 + ((row >> 4) & 7) * 4 +
                 ((row >> 2) & 3);
    unsigned long long pk = 0;
#pragma unroll
    for (int j = 0; j < 4; ++j) {
      int k = (int)((i0 + j) & 255);
      pk |= (unsigned long long)f2bf(Wh[(size_t)k * 1024 + colnat]) << (16 * j);
    }
    *(unsigned long long*)&WhP[i0] = pk;
  }
}

// ---------------------------------------------------------------- xg = x@Wi+b
#define XKP 40  // LDS k-pitch (shorts): 80B rows -> 16B-aligned b128, ~2-way banks
__global__ __launch_bounds__(256) void xg_gemm(const unsigned short* __restrict__ xbf,
                                               const unsigned short* __restrict__ WiT,
                                               const float* __restrict__ bias,
                                               unsigned short* __restrict__ xg) {
  __shared__ unsigned short As[128 * XKP];
  __shared__ unsigned short Bs[128 * XKP];
  const int tid = threadIdx.x;
  const int n0 = blockIdx.x * 128, m0 = blockIdx.y * 128;
  const int wave = tid >> 6, lane = tid & 63, quad = lane >> 4, l16 = lane & 15;
  const int wm = wave >> 1, wn = wave & 1;

  float4v acc[4][4];
#pragma unroll
  for (int i = 0; i < 4; ++i)
#pragma unroll
    for (int j = 0; j < 4; ++j) acc[i][j] = (float4v){0.f, 0.f, 0.f, 0.f};

  const int rr = tid >> 2, c8 = (tid & 3) * 8;  // staging coords (16B per thread)
  for (int k0 = 0; k0 < 256; k0 += 32) {
#pragma unroll
    for (int pp = 0; pp < 2; ++pp) {
      int r = pp * 64 + rr;
      *(uint4*)&As[r * XKP + c8] = *(const uint4*)&xbf[(size_t)(m0 + r) * 256 + k0 + c8];
      *(uint4*)&Bs[r * XKP + c8] = *(const uint4*)&WiT[(size_t)(n0 + r) * 256 + k0 + c8];
    }
    __syncthreads();
#pragma unroll
    for (int mt = 0; mt < 4; ++mt) {
      short8 af = *(const short8*)&As[(wm * 64 + mt * 16 + l16) * XKP + quad * 8];
#pragma unroll
      for (int nt = 0; nt < 4; ++nt) {
        short8 bf = *(const short8*)&Bs[(wn * 64 + nt * 16 + l16) * XKP + quad * 8];
        acc[mt][nt] = __builtin_amdgcn_mfma_f32_16x16x32_bf16(af, bf, acc[mt][nt], 0, 0, 0);
      }
    }
    __syncthreads();
  }
  // epilogue: +bias, bf16 store, PERMUTED layout for the scan:
  //   xg[((b*512 + t)*256 + u)*4 + gate]   (4 gates of a unit contiguous, 8B)
#pragma unroll
  for (int nt = 0; nt < 4; ++nt) {
    int col = n0 + wn * 64 + nt * 16 + l16;
    int gate = col >> 8, u = col & 255;
    float bv = bias[col];
#pragma unroll
    for (int mt = 0; mt < 4; ++mt) {
#pragma unroll
      for (int r = 0; r < 4; ++r) {
        int row = m0 + wm * 64 + mt * 16 + quad * 4 + r;
        int b = row >> 9, t = row & 511;
        xg[(((size_t)b * 512 + t) * 256 + u) * 4 + gate] = f2bf(acc[mt][nt][r] + bv);
      }
    }
  }
}

// ---------------------------------------------------------------- LSTM scan
// 64 WGs, one batch each. 512 threads = 8 waves, 2 waves/SIMD (132KB LDS ->
// 1 WG/CU). Wave w owns Wh rows' [w*128, w*128+128) = 8 tiles (rt 0..7):
//   rt 0..2 -> resident (allocator places in AGPRs; VGPR file holds bufs);
//   rt 3..4 -> LDS slots wave*2+{0,1}, XOR-swizzled;
//   rt 5..7 -> streamed from L2 (sb/sc dedicated buffers, R5 issue points).
// Lane (quad, l16<8) owns unit u = w*32 + l16*4 + quad; act tile rt == l16.
__global__ __launch_bounds__(512, 2) void lstm_scan(
    const unsigned short* __restrict__ WhP,  // [1024][256] bf16 (permuted rows)
    const unsigned short* __restrict__ xg,   // [b][t][u][gate] bf16
    unsigned short* __restrict__ hout) {
  __shared__ unsigned short WhL[16 * 4096];     // 16 slots x 8KB = 131072 B
  __shared__ unsigned short hA[2][256];         // 1 KB, double-buffered h
  const int tid = threadIdx.x;
  const int b = blockIdx.x;  // batch
  const int wave = tid >> 6, lane = tid & 63, quad = lane >> 4, l16 = lane & 15;

  // ---- 3 resident tiles (rt = 0..2)
  short8 frA[3][8];
#pragma unroll
  for (int rt = 0; rt < 3; ++rt) {
    const unsigned short* src =
        WhP + ((size_t)wave * 128 + rt * 16 + l16) * 256 + quad * 8;
#pragma unroll
    for (int kt = 0; kt < 8; ++kt)
      frA[rt][kt] = *(const short8*)&src[kt * 32];
  }
  // ---- 2 LDS tiles (rt = 3,4) -> slots wave*2, wave*2+1, XOR-swizzled
#pragma unroll
  for (int i = 0; i < 16; ++i) {
    int rt = 3 + (i >> 3);
    int chunk = (i & 7) * 64 + lane;     // 512 16B-chunks per tile
    int rw = chunk >> 5, ch = chunk & 31;
    uint4 v = *(const uint4*)&WhP[((size_t)wave * 128 + rt * 16 + rw) * 256 + ch * 8];
    *(uint4*)((char*)WhL + (wave * 2 + rt - 3) * 8192 + rw * 512 +
              ((ch * 16) ^ ((rw & 7) << 4))) = v;
  }
  ((unsigned short*)hA)[tid] = 0;        // h_{-1} = 0 (both buffers; 512 shorts)

  const bool act = (l16 < 8);
  const int u = wave * 32 + l16 * 4 + quad;    // this lane's unit (if act)
  const unsigned short* xgp = xg + ((size_t)b * 512 * 256 + u) * 4;
  unsigned short* houtp = hout + (size_t)b * 512 * 256 + u;
  const char* ldsT = (const char*)WhL + wave * 2 * 8192 + l16 * 512;
  // stream tile bases (loop-invariant -> L2-resident)
  const unsigned short* sp5 = WhP + ((size_t)wave * 128 + 5 * 16 + l16) * 256 + quad * 8;
  const unsigned short* sp6 = WhP + ((size_t)wave * 128 + 6 * 16 + l16) * 256 + quad * 8;
  const unsigned short* sp7 = WhP + ((size_t)wave * 128 + 7 * 16 + l16) * 256 + quad * 8;
  float c = 0.f;
  __syncthreads();

  for (int t = 0; t < 512; ++t) {
    // ---- issue stream tile 5 (consumed in pair45, ~2 pairs later)
    short8 sb[8];
#pragma unroll
    for (int kt = 0; kt < 8; ++kt) sb[kt] = *(const short8*)&sp5[kt * 32];

    // xg(t): 4 gates of this lane's unit, 8B
    unsigned long long xv = 0;
    if (act) xv = *(const unsigned long long*)(xgp + (size_t)t * 1024);

    // h_{t-1} broadcast fragments (conflict-free broadcast reads)
    const char* hbuf = (const char*)hA[t & 1];
    short8 hb8[8];
#pragma unroll
    for (int kt = 0; kt < 8; ++kt)
      hb8[kt] = *(const short8*)(hbuf + kt * 64 + quad * 16);

    float4v g4 = (float4v){0.f, 0.f, 0.f, 0.f};

    // ---- pair (0,1): resident tiles, interleaved chains
    {
      float4v a0 = (float4v){0.f, 0.f, 0.f, 0.f}, a1 = a0;
#pragma unroll
      for (int kt = 0; kt < 8; ++kt) {
        a0 = __builtin_amdgcn_mfma_f32_16x16x32_bf16(frA[0][kt], hb8[kt], a0, 0, 0, 0);
        a1 = __builtin_amdgcn_mfma_f32_16x16x32_bf16(frA[1][kt], hb8[kt], a1, 0, 0, 0);
      }
      if (l16 == 0) g4 = a0;
      if (l16 == 1) g4 = a1;
    }

    // ---- issue stream tile 6 (consumed in pair67)
    short8 sc[8];
#pragma unroll
    for (int kt = 0; kt < 8; ++kt) sc[kt] = *(const short8*)&sp6[kt * 32];

    // ---- pair (2,3): resident tile 2 + LDS tile 0, interleaved
    {
      float4v a0 = (float4v){0.f, 0.f, 0.f, 0.f}, a1 = a0;
#pragma unroll
      for (int kt = 0; kt < 8; ++kt) {
        short8 al = *(const short8*)(ldsT + 0 * 8192 +
                                     ((kt * 64 + quad * 16) ^ ((l16 & 7) << 4)));
        a0 = __builtin_amdgcn_mfma_f32_16x16x32_bf16(frA[2][kt], hb8[kt], a0, 0, 0, 0);
        a1 = __builtin_amdgcn_mfma_f32_16x16x32_bf16(al, hb8[kt], a1, 0, 0, 0);
      }
      if (l16 == 2) g4 = a0;
      if (l16 == 3) g4 = a1;
    }

    // ---- pair (4,5): LDS tile 1 + stream tile 5 (sb), interleaved
    {
      float4v a0 = (float4v){0.f, 0.f, 0.f, 0.f}, a1 = a0;
#pragma unroll
      for (int kt = 0; kt < 8; ++kt) {
        short8 al = *(const short8*)(ldsT + 1 * 8192 +
                                     ((kt * 64 + quad * 16) ^ ((l16 & 7) << 4)));
        a0 = __builtin_amdgcn_mfma_f32_16x16x32_bf16(al, hb8[kt], a0, 0, 0, 0);
        a1 = __builtin_amdgcn_mfma_f32_16x16x32_bf16(sb[kt], hb8[kt], a1, 0, 0, 0);
      }
      if (l16 == 4) g4 = a0;
      if (l16 == 5) g4 = a1;
    }

    // ---- issue stream tile 7 (reuse sb; WAR resolved after pair45 reads)
#pragma unroll
    for (int kt = 0; kt < 8; ++kt) sb[kt] = *(const short8*)&sp7[kt * 32];

    // ---- pair (6,7): stream tiles 6 (sc) + 7 (sb), interleaved
    {
      float4v a0 = (float4v){0.f, 0.f, 0.f, 0.f}, a1 = a0;
#pragma unroll
      for (int kt = 0; kt < 8; ++kt) {
        a0 = __builtin_amdgcn_mfma_f32_16x16x32_bf16(sc[kt], hb8[kt], a0, 0, 0, 0);
        a1 = __builtin_amdgcn_mfma_f32_16x16x32_bf16(sb[kt], hb8[kt], a1, 0, 0, 0);
      }
      if (l16 == 6) g4 = a0;
      if (l16 == 7) g4 = a1;
    }

    // ---- gates (active lanes own one unit each)
    if (act) {
      float gi = g4[0] + bf2f((unsigned short)(xv));
      float gf = g4[1] + bf2f((unsigned short)(xv >> 16));
      float gG = g4[2] + bf2f((unsigned short)(xv >> 32));
      float go = g4[3] + bf2f((unsigned short)(xv >> 48));
      float cc = sigm(gf) * c + sigm(gi) * tanh_f(gG);
      c = cc;
      unsigned short h16 = f2bf(sigm(go) * tanh_f(cc));
      hA[(t + 1) & 1][u] = h16;          // next buffer (disjoint from readers)
      houtp[(size_t)t * 256] = h16;      // h history for attention
    }
    __syncthreads();                     // ONE barrier per step
  }
}

// --------------------------------------------------- attention + head (fused)
__global__ __launch_bounds__(256) void attn_head(
    const unsigned short* __restrict__ hout,
    const float* __restrict__ Wq, const float* __restrict__ bq,
    const float* __restrict__ Wk, const float* __restrict__ bk,
    const float* __restrict__ Wv, const float* __restrict__ bv,
    const float* __restrict__ Wo, const float* __restrict__ bo,
    const float* __restrict__ W1, const float* __restrict__ b1,
    const float* __restrict__ W2, const float* __restrict__ b2,
    float* __restrict__ out) {
  __shared__ float h0S[256], q0S[256], red[256], usS[256], sS[512], hb4[4][256];
  __shared__ float oS[256], o1S[256], zS[32], cbS;
  const int b = blockIdx.x, tid = threadIdx.x, wave = tid >> 6, lane = tid & 63;
  const size_t hb_base = (size_t)b * 512 * 256;

  // ---- q0 = h0@Wq+bq ; u = Wk@(scale*q0) ; cb = scale*q0.bk
  h0S[tid] = bf2f(hout[hb_base + tid]);
  __syncthreads();
  float a = 0.f;
  for (int k = 0; k < 256; ++k) a += h0S[k] * Wq[(size_t)k * 256 + tid];
  q0S[tid] = a + bq[tid];
  __syncthreads();
  red[tid] = q0S[tid] * bk[tid];
  __syncthreads();
  for (int s = 128; s > 0; s >>= 1) {
    if (tid < s) red[tid] += red[tid + s];
    __syncthreads();
  }
  if (tid == 0) cbS = 0.0625f * red[0];
  float acq = 0.f;
  const float* wr = &Wk[(size_t)tid * 256];
  for (int e = 0; e < 256; e += 4) {
    float4 w = *(const float4*)&wr[e];
    acq += w.x * q0S[e] + w.y * q0S[e + 1] + w.z * q0S[e + 2] + w.w * q0S[e + 3];
  }
  usS[tid] = 0.0625f * acq;
  __syncthreads();

  // ---- scores = u.h[b,t]+cb -> softmax -> hbar = sum attn*h
  const float u0 = usS[lane * 4 + 0], u1 = usS[lane * 4 + 1];
  const float u2 = usS[lane * 4 + 2], u3 = usS[lane * 4 + 3];
  const float cbv = cbS;
  for (int i = 0; i < 128; ++i) {
    int t = i * 4 + wave;
    unsigned long long hv = *(const unsigned long long*)&hout[hb_base + (size_t)t * 256 + lane * 4];
    unsigned lo = (unsigned)hv, hi = (unsigned)(hv >> 32);
    float p = u0 * bcl(lo) + u1 * bch(lo) + u2 * bcl(hi) + u3 * bch(hi);
    for (int m = 1; m < 64; m <<= 1) p += __shfl_xor(p, m, 64);
    if (lane == 0) sS[t] = p + cbv;
  }
  __syncthreads();
  red[tid] = fmaxf(sS[tid], sS[tid + 256]);
  __syncthreads();
  for (int s = 128; s > 0; s >>= 1) {
    if (tid < s) red[tid] = fmaxf(red[tid], red[tid + s]);
    __syncthreads();
  }
  float mx = red[0];
  __syncthreads();
  float e0 = __expf(sS[tid] - mx), e1 = __expf(sS[tid + 256] - mx);
  sS[tid] = e0; sS[tid + 256] = e1;
  red[tid] = e0 + e1;
  __syncthreads();
  for (int s = 128; s > 0; s >>= 1) {
    if (tid < s) red[tid] += red[tid + s];
    __syncthreads();
  }
  float inv = 1.f / red[0];
  float a0 = 0.f, a1 = 0.f, a2 = 0.f, a3 = 0.f;
  const int d0 = lane * 4;
  for (int i = 0; i < 128; ++i) {
    int t = wave * 128 + i;
    float w = sS[t];
    unsigned long long hv = *(const unsigned long long*)&hout[hb_base + (size_t)t * 256 + d0];
    unsigned lo = (unsigned)hv, hi = (unsigned)(hv >> 32);
    a0 += w * bcl(lo); a1 += w * bch(lo); a2 += w * bcl(hi); a3 += w * bch(hi);
  }
  hb4[wave][d0] = a0; hb4[wave][d0 + 1] = a1; hb4[wave][d0 + 2] = a2; hb4[wave][d0 + 3] = a3;
  __syncthreads();
  h0S[tid] = (hb4[0][tid] + hb4[1][tid] + hb4[2][tid] + hb4[3][tid]) * inv;  // hbar
  __syncthreads();

  // ---- head: o0=hbar@Wv+bv ; o1=o0@Wo+bo ; z=relu(o1@W1+b1) ; out=z@W2+b2
  a = 0.f;
  for (int k = 0; k < 256; ++k) a += h0S[k] * Wv[(size_t)k * 256 + tid];
  oS[tid] = a + bv[tid];
  __syncthreads();
  a = 0.f;
  for (int k = 0; k < 256; ++k) a += oS[k] * Wo[(size_t)k * 256 + tid];
  o1S[tid] = a + bo[tid];
  __syncthreads();
  if (tid < 32) {
    a = 0.f;
    for (int k = 0; k < 256; ++k) a += o1S[k] * W1[k * 32 + tid];
    zS[tid] = fmaxf(a + b1[tid], 0.f);
  }
  __syncthreads();
  if (tid < 3) {
    a = 0.f;
    for (int j = 0; j < 32; ++j) a += zS[j] * W2[j * 3 + tid];
    out[b * 3 + tid] = a + b2[tid];
  }
}

// ---------------------------------------------------------------- launch
extern "C" void kernel_launch(void* const* d_in, const int* in_sizes, int n_in,
                              void* d_out, int out_size, void* d_ws, size_t ws_size,
                              hipStream_t stream) {
  const float* x  = (const float*)d_in[0];
  const float* Wi = (const float*)d_in[1];
  const float* Wh = (const float*)d_in[2];
  const float* bG = (const float*)d_in[3];
  const float* Wq = (const float*)d_in[4];
  const float* bq = (const float*)d_in[5];
  const float* Wk = (const float*)d_in[6];
  const float* bk = (const float*)d_in[7];
  const float* Wv = (const float*)d_in[8];
  const float* bv = (const float*)d_in[9];
  const float* Wo = (const float*)d_in[10];
  const float* bo = (const float*)d_in[11];
  const float* W1 = (const float*)d_in[12];
  const float* b1 = (const float*)d_in[13];
  const float* W2 = (const float*)d_in[14];
  const float* b2 = (const float*)d_in[15];
  float* out = (float*)d_out;
  char* ws = (char*)d_ws;

  unsigned short* xg   = (unsigned short*)(ws);              // 67,108,864 B
  unsigned short* hout = (unsigned short*)(ws + 67108864);   // 16,777,216 B
  unsigned short* xbf  = (unsigned short*)(ws + 83886080);   // 16,777,216 B
  unsigned short* WiT  = (unsigned short*)(ws + 100663296);  //    524,288 B
  unsigned short* WhP  = (unsigned short*)(ws + 101187584);  //    524,288 B
  // total ~101.7 MB of workspace

  prep_all<<<dim3(8704), dim3(256), 0, stream>>>(x, Wi, Wh, xbf, WiT, WhP);
  xg_gemm<<<dim3(8, 256), dim3(256), 0, stream>>>(xbf, WiT, bG, xg);
  lstm_scan<<<dim3(64), dim3(512), 0, stream>>>(WhP, xg, hout);
  attn_head<<<dim3(64), dim3(256), 0, stream>>>(hout, Wq, bq, Wk, bk, Wv, bv,
                                                Wo, bo, W1, b1, W2, b2, out);
}

// Round 10
// 1260.940 us; speedup vs baseline: 1.2906x; 1.0541x over previous
//
#include <hip/hip_runtime.h>
#include <hip/hip_bf16.h>

// ---------------------------------------------------------------------------
// myLSTM R10: R5 structure RESTORED VERBATIM (best verified: scan 906us,
// total 1161us) + ONE surgical change: hout is staged in LDS and flushed
// coalesced every 16 steps, so the per-step 2B global store no longer sits
// in the barrier's vmcnt(0) drain (~200-300cy exposed at EVERY barrier).
//
// Ledger: R5 = 3 resident + 2 LDS + 3 streamed tiles/wave, single-acc
// passes, 1 barrier/step -> 4240cy/step. Every neighbor regressed:
// R6 (4 resident + pinned waves/eu) +400us, R8 (0 resident) +470us,
// R9 (paired passes) +170us. R5 is a sharp local optimum; the remaining
// identified exposed cost is the store-drain at the barrier (m97 lesson:
// __syncthreads emits s_waitcnt vmcnt(0) which waits for the hout store's
// L2 ack). Flush stores are issued right AFTER a barrier -> ~4000cy of
// distance before the next drain -> fully covered.
//
//   prep_all  : x->bf16 ; Wi -> WiT [1024][256] bf16 ; Wh -> WhP permuted
//               [1024][256] bf16, row' = w*128 + rt*16 + q*4 + r  <->
//               col_nat = gate(r)*256 + unit(w*32 + rt*4 + q).
//   xg_gemm   : xg = x@Wi + b (bf16 MFMA 128x128), PERMUTED [b][t][u][gate].
//   lstm_scan : 64 WGs (one batch each), 512 thr = 8 waves, 2/SIMD.
//               Wave w owns Wh rows' [w*128,+128) = 8 tiles:
//               rt 0..2 resident, rt 3..4 LDS (XOR-swizzled), rt 5..7
//               streamed (sb: tile5 at step top, sc: tile6 after pass 2,
//               sb reload tile7 after pass 5). h_{t-1} (512B) double-
//               buffered in LDS, broadcast B-fragment. Extraction: lane
//               l16==p owns unit w*32 + l16*4 + quad. One barrier/step.
//               NEW: h16 -> hoB[2][16][256] LDS staging; 16-step coalesced
//               flush at step top; final flush after the loop.
//   attn_head : fused attention + MLP head (block-local per batch).
// ---------------------------------------------------------------------------

typedef __attribute__((ext_vector_type(8))) short short8;   // 8 x bf16 (4 VGPR)
typedef __attribute__((ext_vector_type(4))) float float4v;  // MFMA acc

__device__ __forceinline__ unsigned short f2bf(float f) {  // RNE f32->bf16
  unsigned u = __builtin_bit_cast(unsigned, f);
  return (unsigned short)((u + 0x7fffu + ((u >> 16) & 1u)) >> 16);
}
__device__ __forceinline__ float bf2f(unsigned short h) {
  return __builtin_bit_cast(float, ((unsigned)h) << 16);
}
__device__ __forceinline__ float bcl(unsigned u) {  // low bf16 of dword
  return __builtin_bit_cast(float, u << 16);
}
__device__ __forceinline__ float bch(unsigned u) {  // high bf16 of dword
  return __builtin_bit_cast(float, u & 0xffff0000u);
}
// v_rcp_f32 (1 ulp) instead of precise div: error ~1e-7, invisible vs bf16.
__device__ __forceinline__ float sigm(float x) {
  return __builtin_amdgcn_rcpf(1.f + __expf(-x));
}
__device__ __forceinline__ float tanh_f(float x) {
  return 1.f - 2.f * __builtin_amdgcn_rcpf(1.f + __expf(2.f * x));
}

// ---------------------------------------------------------------- prep (fused)
// blocks [0,8192)    : x fp32 -> bf16                (8,388,608 elems)
// blocks [8192,8448) : Wi [256,1024] -> WiT [1024][256] bf16
// blocks [8448,8704) : Wh [256,1024] -> WhP [1024][256] bf16, row-permuted
__global__ void prep_all(const float* __restrict__ x,
                         const float* __restrict__ Wi,
                         const float* __restrict__ Wh,
                         unsigned short* __restrict__ xbf,
                         unsigned short* __restrict__ WiT,
                         unsigned short* __restrict__ WhP) {
  const int bid = blockIdx.x, tid = threadIdx.x;
  if (bid < 8192) {
    size_t i = ((size_t)bid * 256 + tid) * 4;
    float4 v = *(const float4*)&x[i];
    unsigned long long pk = (unsigned long long)f2bf(v.x)
                          | ((unsigned long long)f2bf(v.y) << 16)
                          | ((unsigned long long)f2bf(v.z) << 32)
                          | ((unsigned long long)f2bf(v.w) << 48);
    *(unsigned long long*)&xbf[i] = pk;
  } else if (bid < 8448) {
    size_t i = ((size_t)(bid - 8192) * 256 + tid) * 4;
    float4 v = *(const float4*)&Wi[i];
    int k = (int)(i >> 10), n = (int)(i & 1023);
    WiT[(size_t)(n + 0) * 256 + k] = f2bf(v.x);
    WiT[(size_t)(n + 1) * 256 + k] = f2bf(v.y);
    WiT[(size_t)(n + 2) * 256 + k] = f2bf(v.z);
    WiT[(size_t)(n + 3) * 256 + k] = f2bf(v.w);
  } else {
    size_t i0 = ((size_t)(bid - 8448) * 256 + tid) * 4;
    int row = (int)(i0 >> 8);  // row' (same for all 4 elems)
    // row' = w*128 + rt*16 + q*4 + r -> col_nat = r*256 + w*32 + rt*4 + q
    int colnat = (row & 3) * 256 + (row >> 7) * 32 + ((row >> 4) & 7) * 4 +
                 ((row >> 2) & 3);
    unsigned long long pk = 0;
#pragma unroll
    for (int j = 0; j < 4; ++j) {
      int k = (int)((i0 + j) & 255);
      pk |= (unsigned long long)f2bf(Wh[(size_t)k * 1024 + colnat]) << (16 * j);
    }
    *(unsigned long long*)&WhP[i0] = pk;
  }
}

// ---------------------------------------------------------------- xg = x@Wi+b
#define XKP 40  // LDS k-pitch (shorts): 80B rows -> 16B-aligned b128, ~2-way banks
__global__ __launch_bounds__(256) void xg_gemm(const unsigned short* __restrict__ xbf,
                                               const unsigned short* __restrict__ WiT,
                                               const float* __restrict__ bias,
                                               unsigned short* __restrict__ xg) {
  __shared__ unsigned short As[128 * XKP];
  __shared__ unsigned short Bs[128 * XKP];
  const int tid = threadIdx.x;
  const int n0 = blockIdx.x * 128, m0 = blockIdx.y * 128;
  const int wave = tid >> 6, lane = tid & 63, quad = lane >> 4, l16 = lane & 15;
  const int wm = wave >> 1, wn = wave & 1;

  float4v acc[4][4];
#pragma unroll
  for (int i = 0; i < 4; ++i)
#pragma unroll
    for (int j = 0; j < 4; ++j) acc[i][j] = (float4v){0.f, 0.f, 0.f, 0.f};

  const int rr = tid >> 2, c8 = (tid & 3) * 8;  // staging coords (16B per thread)
  for (int k0 = 0; k0 < 256; k0 += 32) {
#pragma unroll
    for (int pp = 0; pp < 2; ++pp) {
      int r = pp * 64 + rr;
      *(uint4*)&As[r * XKP + c8] = *(const uint4*)&xbf[(size_t)(m0 + r) * 256 + k0 + c8];
      *(uint4*)&Bs[r * XKP + c8] = *(const uint4*)&WiT[(size_t)(n0 + r) * 256 + k0 + c8];
    }
    __syncthreads();
#pragma unroll
    for (int mt = 0; mt < 4; ++mt) {
      short8 af = *(const short8*)&As[(wm * 64 + mt * 16 + l16) * XKP + quad * 8];
#pragma unroll
      for (int nt = 0; nt < 4; ++nt) {
        short8 bf = *(const short8*)&Bs[(wn * 64 + nt * 16 + l16) * XKP + quad * 8];
        acc[mt][nt] = __builtin_amdgcn_mfma_f32_16x16x32_bf16(af, bf, acc[mt][nt], 0, 0, 0);
      }
    }
    __syncthreads();
  }
  // epilogue: +bias, bf16 store, PERMUTED layout for the scan:
  //   xg[((b*512 + t)*256 + u)*4 + gate]   (4 gates of a unit contiguous, 8B)
#pragma unroll
  for (int nt = 0; nt < 4; ++nt) {
    int col = n0 + wn * 64 + nt * 16 + l16;
    int gate = col >> 8, u = col & 255;
    float bv = bias[col];
#pragma unroll
    for (int mt = 0; mt < 4; ++mt) {
#pragma unroll
      for (int r = 0; r < 4; ++r) {
        int row = m0 + wm * 64 + mt * 16 + quad * 4 + r;
        int b = row >> 9, t = row & 511;
        xg[(((size_t)b * 512 + t) * 256 + u) * 4 + gate] = f2bf(acc[mt][nt][r] + bv);
      }
    }
  }
}

// ---------------------------------------------------------------- LSTM scan
// 64 WGs, one batch each. 512 threads = 8 waves, 2 waves/SIMD (145KB LDS ->
// 1 WG/CU). Wave w owns Wh rows' [w*128, w*128+128) = 8 tiles (rt 0..7):
//   rt 0..2 -> resident; rt 3..4 -> LDS slots wave*2+{0,1}, XOR-swizzled;
//   rt 5..7 -> streamed from L2 (sb/sc dedicated buffers, R5 issue points).
// Lane (quad, l16<8) owns unit u = w*32 + l16*4 + quad; act tile rt == l16.
__global__ __launch_bounds__(512, 2) void lstm_scan(
    const unsigned short* __restrict__ WhP,  // [1024][256] bf16 (permuted rows)
    const unsigned short* __restrict__ xg,   // [b][t][u][gate] bf16
    unsigned short* __restrict__ hout) {
  __shared__ unsigned short WhL[16 * 4096];     // 16 slots x 8KB = 131072 B
  __shared__ unsigned short hA[2][256];         // 1 KB, double-buffered h
  __shared__ unsigned short hoB[2][16][256];    // 16 KB, hout staging
  const int tid = threadIdx.x;
  const int b = blockIdx.x;  // batch
  const int wave = tid >> 6, lane = tid & 63, quad = lane >> 4, l16 = lane & 15;

  // ---- 3 resident tiles (rt = 0..2)
  short8 frA[3][8];
#pragma unroll
  for (int rt = 0; rt < 3; ++rt) {
    const unsigned short* src =
        WhP + ((size_t)wave * 128 + rt * 16 + l16) * 256 + quad * 8;
#pragma unroll
    for (int kt = 0; kt < 8; ++kt)
      frA[rt][kt] = *(const short8*)&src[kt * 32];
  }
  // ---- 2 LDS tiles (rt = 3,4) -> slots wave*2, wave*2+1, XOR-swizzled
#pragma unroll
  for (int i = 0; i < 16; ++i) {
    int rt = 3 + (i >> 3);
    int chunk = (i & 7) * 64 + lane;     // 512 16B-chunks per tile
    int rw = chunk >> 5, ch = chunk & 31;
    uint4 v = *(const uint4*)&WhP[((size_t)wave * 128 + rt * 16 + rw) * 256 + ch * 8];
    *(uint4*)((char*)WhL + (wave * 2 + rt - 3) * 8192 + rw * 512 +
              ((ch * 16) ^ ((rw & 7) << 4))) = v;
  }
  ((unsigned short*)hA)[tid] = 0;        // h_{-1} = 0 (both buffers; 512 shorts)

  const bool act = (l16 < 8);
  const int u = wave * 32 + l16 * 4 + quad;    // this lane's unit (if act)
  const unsigned short* xgp = xg + ((size_t)b * 512 * 256 + u) * 4;
  unsigned short* houtb = hout + (size_t)b * 512 * 256;
  const char* ldsT = (const char*)WhL + wave * 2 * 8192 + l16 * 512;
  // stream tile bases (loop-invariant -> L2-resident)
  const unsigned short* sp5 = WhP + ((size_t)wave * 128 + 5 * 16 + l16) * 256 + quad * 8;
  const unsigned short* sp6 = WhP + ((size_t)wave * 128 + 6 * 16 + l16) * 256 + quad * 8;
  const unsigned short* sp7 = WhP + ((size_t)wave * 128 + 7 * 16 + l16) * 256 + quad * 8;
  float c = 0.f;
  __syncthreads();

  for (int t = 0; t < 512; ++t) {
    // ---- coalesced hout flush of the PREVIOUS 16-step half: issued right
    // after a barrier -> ~4000cy before the next vmcnt(0) drain -> covered.
    if ((t & 15) == 0 && t) {
      int hf = ((t >> 4) & 1) ^ 1;
      int row = tid >> 5, u0 = (tid & 31) * 8;
      uint4 hv = *(const uint4*)&hoB[hf][row][u0];
      *(uint4*)&houtb[(size_t)(t - 16 + row) * 256 + u0] = hv;
    }

    // ---- issue stream tile 5 (consumed in pass 5, ~1500cy later)
    short8 sb[8];
#pragma unroll
    for (int kt = 0; kt < 8; ++kt) sb[kt] = *(const short8*)&sp5[kt * 32];

    // xg(t): 4 gates of this lane's unit, 8B
    unsigned long long xv = 0;
    if (act) xv = *(const unsigned long long*)(xgp + (size_t)t * 1024);

    // h_{t-1} broadcast fragments (conflict-free broadcast reads)
    const char* hbuf = (const char*)hA[t & 1];
    short8 hb8[8];
#pragma unroll
    for (int kt = 0; kt < 8; ++kt)
      hb8[kt] = *(const short8*)(hbuf + kt * 64 + quad * 16);

    float4v g4 = (float4v){0.f, 0.f, 0.f, 0.f};

    // ---- passes 0..2: resident tiles
#pragma unroll
    for (int p = 0; p < 3; ++p) {
      float4v a = (float4v){0.f, 0.f, 0.f, 0.f};
#pragma unroll
      for (int kt = 0; kt < 8; ++kt)
        a = __builtin_amdgcn_mfma_f32_16x16x32_bf16(frA[p][kt], hb8[kt], a, 0, 0, 0);
      if (l16 == p) g4 = a;
    }

    // ---- issue stream tile 6 (consumed in pass 6)
    short8 sc[8];
#pragma unroll
    for (int kt = 0; kt < 8; ++kt) sc[kt] = *(const short8*)&sp6[kt * 32];

    // ---- passes 3,4: LDS tiles (swizzled)
#pragma unroll
    for (int p = 0; p < 2; ++p) {
      float4v a = (float4v){0.f, 0.f, 0.f, 0.f};
#pragma unroll
      for (int kt = 0; kt < 8; ++kt) {
        short8 al = *(const short8*)(ldsT + p * 8192 +
                                     ((kt * 64 + quad * 16) ^ ((l16 & 7) << 4)));
        a = __builtin_amdgcn_mfma_f32_16x16x32_bf16(al, hb8[kt], a, 0, 0, 0);
      }
      if (l16 == 3 + p) g4 = a;
    }

    // ---- pass 5: stream tile 5
    {
      float4v a = (float4v){0.f, 0.f, 0.f, 0.f};
#pragma unroll
      for (int kt = 0; kt < 8; ++kt)
        a = __builtin_amdgcn_mfma_f32_16x16x32_bf16(sb[kt], hb8[kt], a, 0, 0, 0);
      if (l16 == 5) g4 = a;
    }
    // ---- issue stream tile 7 (reuse sb; consumed in pass 7)
#pragma unroll
    for (int kt = 0; kt < 8; ++kt) sb[kt] = *(const short8*)&sp7[kt * 32];

    // ---- pass 6: stream tile 6
    {
      float4v a = (float4v){0.f, 0.f, 0.f, 0.f};
#pragma unroll
      for (int kt = 0; kt < 8; ++kt)
        a = __builtin_amdgcn_mfma_f32_16x16x32_bf16(sc[kt], hb8[kt], a, 0, 0, 0);
      if (l16 == 6) g4 = a;
    }
    // ---- pass 7: stream tile 7
    {
      float4v a = (float4v){0.f, 0.f, 0.f, 0.f};
#pragma unroll
      for (int kt = 0; kt < 8; ++kt)
        a = __builtin_amdgcn_mfma_f32_16x16x32_bf16(sb[kt], hb8[kt], a, 0, 0, 0);
      if (l16 == 7) g4 = a;
    }

    // ---- gates (active lanes own one unit each); h -> LDS only (no global
    // store in the barrier's vmcnt(0) drain path)
    if (act) {
      float gi = g4[0] + bf2f((unsigned short)(xv));
      float gf = g4[1] + bf2f((unsigned short)(xv >> 16));
      float gG = g4[2] + bf2f((unsigned short)(xv >> 32));
      float go = g4[3] + bf2f((unsigned short)(xv >> 48));
      float cc = sigm(gf) * c + sigm(gi) * tanh_f(gG);
      c = cc;
      unsigned short h16 = f2bf(sigm(go) * tanh_f(cc));
      hA[(t + 1) & 1][u] = h16;          // next buffer (disjoint from readers)
      hoB[(t >> 4) & 1][t & 15][u] = h16;  // hout staging (LDS)
    }
    __syncthreads();                     // ONE barrier per step
  }
  // ---- final flush: steps 496..511 (half 1)
  {
    int row = tid >> 5, u0 = (tid & 31) * 8;
    uint4 hv = *(const uint4*)&hoB[1][row][u0];
    *(uint4*)&houtb[(size_t)(496 + row) * 256 + u0] = hv;
  }
}

// --------------------------------------------------- attention + head (fused)
__global__ __launch_bounds__(256) void attn_head(
    const unsigned short* __restrict__ hout,
    const float* __restrict__ Wq, const float* __restrict__ bq,
    const float* __restrict__ Wk, const float* __restrict__ bk,
    const float* __restrict__ Wv, const float* __restrict__ bv,
    const float* __restrict__ Wo, const float* __restrict__ bo,
    const float* __restrict__ W1, const float* __restrict__ b1,
    const float* __restrict__ W2, const float* __restrict__ b2,
    float* __restrict__ out) {
  __shared__ float h0S[256], q0S[256], red[256], usS[256], sS[512], hb4[4][256];
  __shared__ float oS[256], o1S[256], zS[32], cbS;
  const int b = blockIdx.x, tid = threadIdx.x, wave = tid >> 6, lane = tid & 63;
  const size_t hb_base = (size_t)b * 512 * 256;

  // ---- q0 = h0@Wq+bq ; u = Wk@(scale*q0) ; cb = scale*q0.bk
  h0S[tid] = bf2f(hout[hb_base + tid]);
  __syncthreads();
  float a = 0.f;
  for (int k = 0; k < 256; ++k) a += h0S[k] * Wq[(size_t)k * 256 + tid];
  q0S[tid] = a + bq[tid];
  __syncthreads();
  red[tid] = q0S[tid] * bk[tid];
  __syncthreads();
  for (int s = 128; s > 0; s >>= 1) {
    if (tid < s) red[tid] += red[tid + s];
    __syncthreads();
  }
  if (tid == 0) cbS = 0.0625f * red[0];
  float acq = 0.f;
  const float* wr = &Wk[(size_t)tid * 256];
  for (int e = 0; e < 256; e += 4) {
    float4 w = *(const float4*)&wr[e];
    acq += w.x * q0S[e] + w.y * q0S[e + 1] + w.z * q0S[e + 2] + w.w * q0S[e + 3];
  }
  usS[tid] = 0.0625f * acq;
  __syncthreads();

  // ---- scores = u.h[b,t]+cb -> softmax -> hbar = sum attn*h
  const float u0 = usS[lane * 4 + 0], u1 = usS[lane * 4 + 1];
  const float u2 = usS[lane * 4 + 2], u3 = usS[lane * 4 + 3];
  const float cbv = cbS;
  for (int i = 0; i < 128; ++i) {
    int t = i * 4 + wave;
    unsigned long long hv = *(const unsigned long long*)&hout[hb_base + (size_t)t * 256 + lane * 4];
    unsigned lo = (unsigned)hv, hi = (unsigned)(hv >> 32);
    float p = u0 * bcl(lo) + u1 * bch(lo) + u2 * bcl(hi) + u3 * bch(hi);
    for (int m = 1; m < 64; m <<= 1) p += __shfl_xor(p, m, 64);
    if (lane == 0) sS[t] = p + cbv;
  }
  __syncthreads();
  red[tid] = fmaxf(sS[tid], sS[tid + 256]);
  __syncthreads();
  for (int s = 128; s > 0; s >>= 1) {
    if (tid < s) red[tid] = fmaxf(red[tid], red[tid + s]);
    __syncthreads();
  }
  float mx = red[0];
  __syncthreads();
  float e0 = __expf(sS[tid] - mx), e1 = __expf(sS[tid + 256] - mx);
  sS[tid] = e0; sS[tid + 256] = e1;
  red[tid] = e0 + e1;
  __syncthreads();
  for (int s = 128; s > 0; s >>= 1) {
    if (tid < s) red[tid] += red[tid + s];
    __syncthreads();
  }
  float inv = 1.f / red[0];
  float a0 = 0.f, a1 = 0.f, a2 = 0.f, a3 = 0.f;
  const int d0 = lane * 4;
  for (int i = 0; i < 128; ++i) {
    int t = wave * 128 + i;
    float w = sS[t];
    unsigned long long hv = *(const unsigned long long*)&hout[hb_base + (size_t)t * 256 + d0];
    unsigned lo = (unsigned)hv, hi = (unsigned)(hv >> 32);
    a0 += w * bcl(lo); a1 += w * bch(lo); a2 += w * bcl(hi); a3 += w * bch(hi);
  }
  hb4[wave][d0] = a0; hb4[wave][d0 + 1] = a1; hb4[wave][d0 + 2] = a2; hb4[wave][d0 + 3] = a3;
  __syncthreads();
  h0S[tid] = (hb4[0][tid] + hb4[1][tid] + hb4[2][tid] + hb4[3][tid]) * inv;  // hbar
  __syncthreads();

  // ---- head: o0=hbar@Wv+bv ; o1=o0@Wo+bo ; z=relu(o1@W1+b1) ; out=z@W2+b2
  a = 0.f;
  for (int k = 0; k < 256; ++k) a += h0S[k] * Wv[(size_t)k * 256 + tid];
  oS[tid] = a + bv[tid];
  __syncthreads();
  a = 0.f;
  for (int k = 0; k < 256; ++k) a += oS[k] * Wo[(size_t)k * 256 + tid];
  o1S[tid] = a + bo[tid];
  __syncthreads();
  if (tid < 32) {
    a = 0.f;
    for (int k = 0; k < 256; ++k) a += o1S[k] * W1[k * 32 + tid];
    zS[tid] = fmaxf(a + b1[tid], 0.f);
  }
  __syncthreads();
  if (tid < 3) {
    a = 0.f;
    for (int j = 0; j < 32; ++j) a += zS[j] * W2[j * 3 + tid];
    out[b * 3 + tid] = a + b2[tid];
  }
}

// ---------------------------------------------------------------- launch
extern "C" void kernel_launch(void* const* d_in, const int* in_sizes, int n_in,
                              void* d_out, int out_size, void* d_ws, size_t ws_size,
                              hipStream_t stream) {
  const float* x  = (const float*)d_in[0];
  const float* Wi = (const float*)d_in[1];
  const float* Wh = (const float*)d_in[2];
  const float* bG = (const float*)d_in[3];
  const float* Wq = (const float*)d_in[4];
  const float* bq = (const float*)d_in[5];
  const float* Wk = (const float*)d_in[6];
  const float* bk = (const float*)d_in[7];
  const float* Wv = (const float*)d_in[8];
  const float* bv = (const float*)d_in[9];
  const float* Wo = (const float*)d_in[10];
  const float* bo = (const float*)d_in[11];
  const float* W1 = (const float*)d_in[12];
  const float* b1 = (const float*)d_in[13];
  const float* W2 = (const float*)d_in[14];
  const float* b2 = (const float*)d_in[15];
  float* out = (float*)d_out;
  char* ws = (char*)d_ws;

  unsigned short* xg   = (unsigned short*)(ws);              // 67,108,864 B
  unsigned short* hout = (unsigned short*)(ws + 67108864);   // 16,777,216 B
  unsigned short* xbf  = (unsigned short*)(ws + 83886080);   // 16,777,216 B
  unsigned short* WiT  = (unsigned short*)(ws + 100663296);  //    524,288 B
  unsigned short* WhP  = (unsigned short*)(ws + 101187584);  //    524,288 B
  // total ~101.7 MB of workspace

  prep_all<<<dim3(8704), dim3(256), 0, stream>>>(x, Wi, Wh, xbf, WiT, WhP);
  xg_gemm<<<dim3(8, 256), dim3(256), 0, stream>>>(xbf, WiT, bG, xg);
  lstm_scan<<<dim3(64), dim3(512), 0, stream>>>(WhP, xg, hout);
  attn_head<<<dim3(64), dim3(256), 0, stream>>>(hout, Wq, bq, Wk, bk, Wv, bv,
                                                Wo, bo, W1, b1, W2, b2, out);
}

// Round 11
// 1168.709 us; speedup vs baseline: 1.3924x; 1.0789x over previous
//
#include <hip/hip_runtime.h>
#include <hip/hip_bf16.h>

// ---------------------------------------------------------------------------
// myLSTM R11: R5 (best verified: scan 906us) with ONE register-neutral swap:
// a 4th resident Wh tile replaces one streamed tile; the sc stream buffer is
// deleted to pay for it (+32 frA AGPR, -32 sc VGPR -> total ~222/256, R5's
// proven-safe pressure point).
//
// Model (fits R5/R6/R8/R10 within ~5%): step time = (non-resident Wh bytes
// per CU)/64B-per-cy L1 return path + ~1100cy overhead. R5: 192KB -> 4240cy.
// R11: 128KB -> ~3550-3750cy (one ~250cy WAR reload exposed). R10's hoB
// staging REVERTED (stores queued ahead of stream loads in vmcnt order).
//
//   prep_all  : x->bf16 ; Wi -> WiT [1024][256] bf16 ; Wh -> WhP permuted
//               [1024][256] bf16, row' = w*128 + rt*16 + q*4 + r  <->
//               col_nat = gate(r)*256 + unit(w*32 + rt*4 + q).
//   xg_gemm   : xg = x@Wi + b (bf16 MFMA 128x128), PERMUTED [b][t][u][gate].
//   lstm_scan : 64 WGs (one batch each), 512 thr = 8 waves, 2/SIMD.
//               Wave w owns Wh rows' [w*128,+128) = 8 tiles:
//               rt 0..3 resident (frA, allocator -> AGPR), rt 4,6 LDS slots
//               wave*2+{0,1} (XOR-swizzled), rt 5,7 streamed through ONE sb
//               buffer: tile5 loaded at step top (consumed pass 5), tile7
//               reloaded after pass 5 (LDS pass 6 covers part of the WAR),
//               consumed pass 7. h_{t-1} (512B) double-buffered in LDS,
//               broadcast B-fragment. Extraction: lane l16==p owns unit
//               w*32 + l16*4 + quad. Per-step hout store (R5 form).
//               One barrier/step.
//   attn_head : fused attention + MLP head (block-local per batch).
// ---------------------------------------------------------------------------

typedef __attribute__((ext_vector_type(8))) short short8;   // 8 x bf16 (4 VGPR)
typedef __attribute__((ext_vector_type(4))) float float4v;  // MFMA acc

__device__ __forceinline__ unsigned short f2bf(float f) {  // RNE f32->bf16
  unsigned u = __builtin_bit_cast(unsigned, f);
  return (unsigned short)((u + 0x7fffu + ((u >> 16) & 1u)) >> 16);
}
__device__ __forceinline__ float bf2f(unsigned short h) {
  return __builtin_bit_cast(float, ((unsigned)h) << 16);
}
__device__ __forceinline__ float bcl(unsigned u) {  // low bf16 of dword
  return __builtin_bit_cast(float, u << 16);
}
__device__ __forceinline__ float bch(unsigned u) {  // high bf16 of dword
  return __builtin_bit_cast(float, u & 0xffff0000u);
}
// v_rcp_f32 (1 ulp) instead of precise div: error ~1e-7, invisible vs bf16.
__device__ __forceinline__ float sigm(float x) {
  return __builtin_amdgcn_rcpf(1.f + __expf(-x));
}
__device__ __forceinline__ float tanh_f(float x) {
  return 1.f - 2.f * __builtin_amdgcn_rcpf(1.f + __expf(2.f * x));
}

// ---------------------------------------------------------------- prep (fused)
// blocks [0,8192)    : x fp32 -> bf16                (8,388,608 elems)
// blocks [8192,8448) : Wi [256,1024] -> WiT [1024][256] bf16
// blocks [8448,8704) : Wh [256,1024] -> WhP [1024][256] bf16, row-permuted
__global__ void prep_all(const float* __restrict__ x,
                         const float* __restrict__ Wi,
                         const float* __restrict__ Wh,
                         unsigned short* __restrict__ xbf,
                         unsigned short* __restrict__ WiT,
                         unsigned short* __restrict__ WhP) {
  const int bid = blockIdx.x, tid = threadIdx.x;
  if (bid < 8192) {
    size_t i = ((size_t)bid * 256 + tid) * 4;
    float4 v = *(const float4*)&x[i];
    unsigned long long pk = (unsigned long long)f2bf(v.x)
                          | ((unsigned long long)f2bf(v.y) << 16)
                          | ((unsigned long long)f2bf(v.z) << 32)
                          | ((unsigned long long)f2bf(v.w) << 48);
    *(unsigned long long*)&xbf[i] = pk;
  } else if (bid < 8448) {
    size_t i = ((size_t)(bid - 8192) * 256 + tid) * 4;
    float4 v = *(const float4*)&Wi[i];
    int k = (int)(i >> 10), n = (int)(i & 1023);
    WiT[(size_t)(n + 0) * 256 + k] = f2bf(v.x);
    WiT[(size_t)(n + 1) * 256 + k] = f2bf(v.y);
    WiT[(size_t)(n + 2) * 256 + k] = f2bf(v.z);
    WiT[(size_t)(n + 3) * 256 + k] = f2bf(v.w);
  } else {
    size_t i0 = ((size_t)(bid - 8448) * 256 + tid) * 4;
    int row = (int)(i0 >> 8);  // row' (same for all 4 elems)
    // row' = w*128 + rt*16 + q*4 + r -> col_nat = r*256 + w*32 + rt*4 + q
    int colnat = (row & 3) * 256 + (row >> 7) * 32 + ((row >> 4) & 7) * 4 +
                 ((row >> 2) & 3);
    unsigned long long pk = 0;
#pragma unroll
    for (int j = 0; j < 4; ++j) {
      int k = (int)((i0 + j) & 255);
      pk |= (unsigned long long)f2bf(Wh[(size_t)k * 1024 + colnat]) << (16 * j);
    }
    *(unsigned long long*)&WhP[i0] = pk;
  }
}

// ---------------------------------------------------------------- xg = x@Wi+b
#define XKP 40  // LDS k-pitch (shorts): 80B rows -> 16B-aligned b128, ~2-way banks
__global__ __launch_bounds__(256) void xg_gemm(const unsigned short* __restrict__ xbf,
                                               const unsigned short* __restrict__ WiT,
                                               const float* __restrict__ bias,
                                               unsigned short* __restrict__ xg) {
  __shared__ unsigned short As[128 * XKP];
  __shared__ unsigned short Bs[128 * XKP];
  const int tid = threadIdx.x;
  const int n0 = blockIdx.x * 128, m0 = blockIdx.y * 128;
  const int wave = tid >> 6, lane = tid & 63, quad = lane >> 4, l16 = lane & 15;
  const int wm = wave >> 1, wn = wave & 1;

  float4v acc[4][4];
#pragma unroll
  for (int i = 0; i < 4; ++i)
#pragma unroll
    for (int j = 0; j < 4; ++j) acc[i][j] = (float4v){0.f, 0.f, 0.f, 0.f};

  const int rr = tid >> 2, c8 = (tid & 3) * 8;  // staging coords (16B per thread)
  for (int k0 = 0; k0 < 256; k0 += 32) {
#pragma unroll
    for (int pp = 0; pp < 2; ++pp) {
      int r = pp * 64 + rr;
      *(uint4*)&As[r * XKP + c8] = *(const uint4*)&xbf[(size_t)(m0 + r) * 256 + k0 + c8];
      *(uint4*)&Bs[r * XKP + c8] = *(const uint4*)&WiT[(size_t)(n0 + r) * 256 + k0 + c8];
    }
    __syncthreads();
#pragma unroll
    for (int mt = 0; mt < 4; ++mt) {
      short8 af = *(const short8*)&As[(wm * 64 + mt * 16 + l16) * XKP + quad * 8];
#pragma unroll
      for (int nt = 0; nt < 4; ++nt) {
        short8 bf = *(const short8*)&Bs[(wn * 64 + nt * 16 + l16) * XKP + quad * 8];
        acc[mt][nt] = __builtin_amdgcn_mfma_f32_16x16x32_bf16(af, bf, acc[mt][nt], 0, 0, 0);
      }
    }
    __syncthreads();
  }
  // epilogue: +bias, bf16 store, PERMUTED layout for the scan:
  //   xg[((b*512 + t)*256 + u)*4 + gate]   (4 gates of a unit contiguous, 8B)
#pragma unroll
  for (int nt = 0; nt < 4; ++nt) {
    int col = n0 + wn * 64 + nt * 16 + l16;
    int gate = col >> 8, u = col & 255;
    float bv = bias[col];
#pragma unroll
    for (int mt = 0; mt < 4; ++mt) {
#pragma unroll
      for (int r = 0; r < 4; ++r) {
        int row = m0 + wm * 64 + mt * 16 + quad * 4 + r;
        int b = row >> 9, t = row & 511;
        xg[(((size_t)b * 512 + t) * 256 + u) * 4 + gate] = f2bf(acc[mt][nt][r] + bv);
      }
    }
  }
}

// ---------------------------------------------------------------- LSTM scan
// 64 WGs, one batch each. 512 threads = 8 waves, 2 waves/SIMD (132KB LDS ->
// 1 WG/CU; ~222/256 unified regs per wave). Wave w owns Wh rows'
// [w*128, w*128+128) = 8 tiles (rt 0..7):
//   rt 0..3 -> resident (frA; allocator spills to AGPR, free for MFMA-A);
//   rt 4,6  -> LDS slots wave*2+{0,1}, XOR-swizzled;
//   rt 5,7  -> streamed through ONE sb buffer (tile5 @ step top -> pass 5;
//              tile7 reloaded after pass 5 -> pass 7, LDS pass 6 in between).
// Lane (quad, l16<8) owns unit u = w*32 + l16*4 + quad; act tile rt == l16.
__global__ __launch_bounds__(512, 2) void lstm_scan(
    const unsigned short* __restrict__ WhP,  // [1024][256] bf16 (permuted rows)
    const unsigned short* __restrict__ xg,   // [b][t][u][gate] bf16
    unsigned short* __restrict__ hout) {
  __shared__ unsigned short WhL[16 * 4096];     // 16 slots x 8KB = 131072 B
  __shared__ unsigned short hA[2][256];         // 1 KB, double-buffered h
  const int tid = threadIdx.x;
  const int b = blockIdx.x;  // batch
  const int wave = tid >> 6, lane = tid & 63, quad = lane >> 4, l16 = lane & 15;

  // ---- 4 resident tiles (rt = 0..3)
  short8 frA[4][8];
#pragma unroll
  for (int rt = 0; rt < 4; ++rt) {
    const unsigned short* src =
        WhP + ((size_t)wave * 128 + rt * 16 + l16) * 256 + quad * 8;
#pragma unroll
    for (int kt = 0; kt < 8; ++kt)
      frA[rt][kt] = *(const short8*)&src[kt * 32];
  }
  // ---- 2 LDS tiles (rt = 4,6) -> slots wave*2, wave*2+1, XOR-swizzled
#pragma unroll
  for (int i = 0; i < 16; ++i) {
    int j = i >> 3;                      // 0 -> rt 4, 1 -> rt 6
    int rt = 4 + 2 * j;
    int chunk = (i & 7) * 64 + lane;     // 512 16B-chunks per tile
    int rw = chunk >> 5, ch = chunk & 31;
    uint4 v = *(const uint4*)&WhP[((size_t)wave * 128 + rt * 16 + rw) * 256 + ch * 8];
    *(uint4*)((char*)WhL + (wave * 2 + j) * 8192 + rw * 512 +
              ((ch * 16) ^ ((rw & 7) << 4))) = v;
  }
  ((unsigned short*)hA)[tid] = 0;        // h_{-1} = 0 (both buffers; 512 shorts)

  const bool act = (l16 < 8);
  const int u = wave * 32 + l16 * 4 + quad;    // this lane's unit (if act)
  const unsigned short* xgp = xg + ((size_t)b * 512 * 256 + u) * 4;
  unsigned short* houtp = hout + (size_t)b * 512 * 256 + u;
  const char* ldsT = (const char*)WhL + wave * 2 * 8192 + l16 * 512;
  // stream tile bases (loop-invariant -> L2-resident)
  const unsigned short* sp5 = WhP + ((size_t)wave * 128 + 5 * 16 + l16) * 256 + quad * 8;
  const unsigned short* sp7 = WhP + ((size_t)wave * 128 + 7 * 16 + l16) * 256 + quad * 8;
  float c = 0.f;
  __syncthreads();

  for (int t = 0; t < 512; ++t) {
    // ---- issue stream tile 5 (consumed in pass 5, ~2000cy later)
    short8 sb[8];
#pragma unroll
    for (int kt = 0; kt < 8; ++kt) sb[kt] = *(const short8*)&sp5[kt * 32];

    // xg(t): 4 gates of this lane's unit, 8B
    unsigned long long xv = 0;
    if (act) xv = *(const unsigned long long*)(xgp + (size_t)t * 1024);

    // h_{t-1} broadcast fragments (conflict-free broadcast reads)
    const char* hbuf = (const char*)hA[t & 1];
    short8 hb8[8];
#pragma unroll
    for (int kt = 0; kt < 8; ++kt)
      hb8[kt] = *(const short8*)(hbuf + kt * 64 + quad * 16);

    float4v g4 = (float4v){0.f, 0.f, 0.f, 0.f};

    // ---- passes 0..3: resident tiles
#pragma unroll
    for (int p = 0; p < 4; ++p) {
      float4v a = (float4v){0.f, 0.f, 0.f, 0.f};
#pragma unroll
      for (int kt = 0; kt < 8; ++kt)
        a = __builtin_amdgcn_mfma_f32_16x16x32_bf16(frA[p][kt], hb8[kt], a, 0, 0, 0);
      if (l16 == p) g4 = a;
    }

    // ---- pass 4: LDS slot 0 (tile rt=4, swizzled)
    {
      float4v a = (float4v){0.f, 0.f, 0.f, 0.f};
#pragma unroll
      for (int kt = 0; kt < 8; ++kt) {
        short8 al = *(const short8*)(ldsT + 0 * 8192 +
                                     ((kt * 64 + quad * 16) ^ ((l16 & 7) << 4)));
        a = __builtin_amdgcn_mfma_f32_16x16x32_bf16(al, hb8[kt], a, 0, 0, 0);
      }
      if (l16 == 4) g4 = a;
    }

    // ---- pass 5: stream tile 5 (sb)
    {
      float4v a = (float4v){0.f, 0.f, 0.f, 0.f};
#pragma unroll
      for (int kt = 0; kt < 8; ++kt)
        a = __builtin_amdgcn_mfma_f32_16x16x32_bf16(sb[kt], hb8[kt], a, 0, 0, 0);
      if (l16 == 5) g4 = a;
    }
    // ---- reload sb = tile 7 (WAR on pass-5 reads; LDS pass 6 covers part
    // of the ~250cy latency, co-resident wave covers the rest)
#pragma unroll
    for (int kt = 0; kt < 8; ++kt) sb[kt] = *(const short8*)&sp7[kt * 32];

    // ---- pass 6: LDS slot 1 (tile rt=6, swizzled)
    {
      float4v a = (float4v){0.f, 0.f, 0.f, 0.f};
#pragma unroll
      for (int kt = 0; kt < 8; ++kt) {
        short8 al = *(const short8*)(ldsT + 1 * 8192 +
                                     ((kt * 64 + quad * 16) ^ ((l16 & 7) << 4)));
        a = __builtin_amdgcn_mfma_f32_16x16x32_bf16(al, hb8[kt], a, 0, 0, 0);
      }
      if (l16 == 6) g4 = a;
    }

    // ---- pass 7: stream tile 7 (sb)
    {
      float4v a = (float4v){0.f, 0.f, 0.f, 0.f};
#pragma unroll
      for (int kt = 0; kt < 8; ++kt)
        a = __builtin_amdgcn_mfma_f32_16x16x32_bf16(sb[kt], hb8[kt], a, 0, 0, 0);
      if (l16 == 7) g4 = a;
    }

    // ---- gates (active lanes own one unit each)
    if (act) {
      float gi = g4[0] + bf2f((unsigned short)(xv));
      float gf = g4[1] + bf2f((unsigned short)(xv >> 16));
      float gG = g4[2] + bf2f((unsigned short)(xv >> 32));
      float go = g4[3] + bf2f((unsigned short)(xv >> 48));
      float cc = sigm(gf) * c + sigm(gi) * tanh_f(gG);
      c = cc;
      unsigned short h16 = f2bf(sigm(go) * tanh_f(cc));
      hA[(t + 1) & 1][u] = h16;          // next buffer (disjoint from readers)
      houtp[(size_t)t * 256] = h16;      // h history for attention (R5 form)
    }
    __syncthreads();                     // ONE barrier per step
  }
}

// --------------------------------------------------- attention + head (fused)
__global__ __launch_bounds__(256) void attn_head(
    const unsigned short* __restrict__ hout,
    const float* __restrict__ Wq, const float* __restrict__ bq,
    const float* __restrict__ Wk, const float* __restrict__ bk,
    const float* __restrict__ Wv, const float* __restrict__ bv,
    const float* __restrict__ Wo, const float* __restrict__ bo,
    const float* __restrict__ W1, const float* __restrict__ b1,
    const float* __restrict__ W2, const float* __restrict__ b2,
    float* __restrict__ out) {
  __shared__ float h0S[256], q0S[256], red[256], usS[256], sS[512], hb4[4][256];
  __shared__ float oS[256], o1S[256], zS[32], cbS;
  const int b = blockIdx.x, tid = threadIdx.x, wave = tid >> 6, lane = tid & 63;
  const size_t hb_base = (size_t)b * 512 * 256;

  // ---- q0 = h0@Wq+bq ; u = Wk@(scale*q0) ; cb = scale*q0.bk
  h0S[tid] = bf2f(hout[hb_base + tid]);
  __syncthreads();
  float a = 0.f;
  for (int k = 0; k < 256; ++k) a += h0S[k] * Wq[(size_t)k * 256 + tid];
  q0S[tid] = a + bq[tid];
  __syncthreads();
  red[tid] = q0S[tid] * bk[tid];
  __syncthreads();
  for (int s = 128; s > 0; s >>= 1) {
    if (tid < s) red[tid] += red[tid + s];
    __syncthreads();
  }
  if (tid == 0) cbS = 0.0625f * red[0];
  float acq = 0.f;
  const float* wr = &Wk[(size_t)tid * 256];
  for (int e = 0; e < 256; e += 4) {
    float4 w = *(const float4*)&wr[e];
    acq += w.x * q0S[e] + w.y * q0S[e + 1] + w.z * q0S[e + 2] + w.w * q0S[e + 3];
  }
  usS[tid] = 0.0625f * acq;
  __syncthreads();

  // ---- scores = u.h[b,t]+cb -> softmax -> hbar = sum attn*h
  const float u0 = usS[lane * 4 + 0], u1 = usS[lane * 4 + 1];
  const float u2 = usS[lane * 4 + 2], u3 = usS[lane * 4 + 3];
  const float cbv = cbS;
  for (int i = 0; i < 128; ++i) {
    int t = i * 4 + wave;
    unsigned long long hv = *(const unsigned long long*)&hout[hb_base + (size_t)t * 256 + lane * 4];
    unsigned lo = (unsigned)hv, hi = (unsigned)(hv >> 32);
    float p = u0 * bcl(lo) + u1 * bch(lo) + u2 * bcl(hi) + u3 * bch(hi);
    for (int m = 1; m < 64; m <<= 1) p += __shfl_xor(p, m, 64);
    if (lane == 0) sS[t] = p + cbv;
  }
  __syncthreads();
  red[tid] = fmaxf(sS[tid], sS[tid + 256]);
  __syncthreads();
  for (int s = 128; s > 0; s >>= 1) {
    if (tid < s) red[tid] = fmaxf(red[tid], red[tid + s]);
    __syncthreads();
  }
  float mx = red[0];
  __syncthreads();
  float e0 = __expf(sS[tid] - mx), e1 = __expf(sS[tid + 256] - mx);
  sS[tid] = e0; sS[tid + 256] = e1;
  red[tid] = e0 + e1;
  __syncthreads();
  for (int s = 128; s > 0; s >>= 1) {
    if (tid < s) red[tid] += red[tid + s];
    __syncthreads();
  }
  float inv = 1.f / red[0];
  float a0 = 0.f, a1 = 0.f, a2 = 0.f, a3 = 0.f;
  const int d0 = lane * 4;
  for (int i = 0; i < 128; ++i) {
    int t = wave * 128 + i;
    float w = sS[t];
    unsigned long long hv = *(const unsigned long long*)&hout[hb_base + (size_t)t * 256 + d0];
    unsigned lo = (unsigned)hv, hi = (unsigned)(hv >> 32);
    a0 += w * bcl(lo); a1 += w * bch(lo); a2 += w * bcl(hi); a3 += w * bch(hi);
  }
  hb4[wave][d0] = a0; hb4[wave][d0 + 1] = a1; hb4[wave][d0 + 2] = a2; hb4[wave][d0 + 3] = a3;
  __syncthreads();
  h0S[tid] = (hb4[0][tid] + hb4[1][tid] + hb4[2][tid] + hb4[3][tid]) * inv;  // hbar
  __syncthreads();

  // ---- head: o0=hbar@Wv+bv ; o1=o0@Wo+bo ; z=relu(o1@W1+b1) ; out=z@W2+b2
  a = 0.f;
  for (int k = 0; k < 256; ++k) a += h0S[k] * Wv[(size_t)k * 256 + tid];
  oS[tid] = a + bv[tid];
  __syncthreads();
  a = 0.f;
  for (int k = 0; k < 256; ++k) a += oS[k] * Wo[(size_t)k * 256 + tid];
  o1S[tid] = a + bo[tid];
  __syncthreads();
  if (tid < 32) {
    a = 0.f;
    for (int k = 0; k < 256; ++k) a += o1S[k] * W1[k * 32 + tid];
    zS[tid] = fmaxf(a + b1[tid], 0.f);
  }
  __syncthreads();
  if (tid < 3) {
    a = 0.f;
    for (int j = 0; j < 32; ++j) a += zS[j] * W2[j * 3 + tid];
    out[b * 3 + tid] = a + b2[tid];
  }
}

// ---------------------------------------------------------------- launch
extern "C" void kernel_launch(void* const* d_in, const int* in_sizes, int n_in,
                              void* d_out, int out_size, void* d_ws, size_t ws_size,
                              hipStream_t stream) {
  const float* x  = (const float*)d_in[0];
  const float* Wi = (const float*)d_in[1];
  const float* Wh = (const float*)d_in[2];
  const float* bG = (const float*)d_in[3];
  const float* Wq = (const float*)d_in[4];
  const float* bq = (const float*)d_in[5];
  const float* Wk = (const float*)d_in[6];
  const float* bk = (const float*)d_in[7];
  const float* Wv = (const float*)d_in[8];
  const float* bv = (const float*)d_in[9];
  const float* Wo = (const float*)d_in[10];
  const float* bo = (const float*)d_in[11];
  const float* W1 = (const float*)d_in[12];
  const float* b1 = (const float*)d_in[13];
  const float* W2 = (const float*)d_in[14];
  const float* b2 = (const float*)d_in[15];
  float* out = (float*)d_out;
  char* ws = (char*)d_ws;

  unsigned short* xg   = (unsigned short*)(ws);              // 67,108,864 B
  unsigned short* hout = (unsigned short*)(ws + 67108864);   // 16,777,216 B
  unsigned short* xbf  = (unsigned short*)(ws + 83886080);   // 16,777,216 B
  unsigned short* WiT  = (unsigned short*)(ws + 100663296);  //    524,288 B
  unsigned short* WhP  = (unsigned short*)(ws + 101187584);  //    524,288 B
  // total ~101.7 MB of workspace

  prep_all<<<dim3(8704), dim3(256), 0, stream>>>(x, Wi, Wh, xbf, WiT, WhP);
  xg_gemm<<<dim3(8, 256), dim3(256), 0, stream>>>(xbf, WiT, bG, xg);
  lstm_scan<<<dim3(64), dim3(512), 0, stream>>>(WhP, xg, hout);
  attn_head<<<dim3(64), dim3(256), 0, stream>>>(hout, Wq, bq, Wk, bk, Wv, bv,
                                                Wo, bo, W1, b1, W2, b2, out);
}